// Round 7
// baseline (297.020 us; speedup 1.0000x reference)
//
#include <hip/hip_runtime.h>
#include <hip/hip_bf16.h>

#define BB 8
#define SS 2048
#define DD 256
#define CC 32
#define HH 4
#define HD 64
#define MTOT (BB*SS)   // 16384 tokens

using bf16    = __hip_bfloat16;
using short8  = __attribute__((ext_vector_type(8))) short;
using short4v = __attribute__((ext_vector_type(4))) short;
using floatx4 = __attribute__((ext_vector_type(4))) float;

#if __has_builtin(__builtin_amdgcn_mfma_f32_16x16x16_bf16)
  #define MFMA_PV16(a,b,c) __builtin_amdgcn_mfma_f32_16x16x16_bf16(a,b,c,0,0,0)
  #define HAVE_PV16 1
#elif __has_builtin(__builtin_amdgcn_mfma_f32_16x16x16bf16_1k)
  #define MFMA_PV16(a,b,c) __builtin_amdgcn_mfma_f32_16x16x16bf16_1k(a,b,c,0,0,0)
  #define HAVE_PV16 1
#else
  #define HAVE_PV16 0
#endif

#if __has_builtin(__builtin_amdgcn_global_load_lds)
  #define HAVE_GLL 1
#else
  #define HAVE_GLL 0
#endif

__device__ inline float bf2f(unsigned short u) {
    union { unsigned int i; float f; } v; v.i = ((unsigned int)u) << 16; return v.f;
}
__device__ inline unsigned short f2bfbits(float f) {
    bf16 h = __float2bfloat16(f);
    return __builtin_bit_cast(unsigned short, h);
}

// --------------------------------------------------------------------------
#define N_X    (MTOT*DD)
#define N_COND (MTOT*CC)
#define N_WQW  (DD*DD)
#define N_WQB  (DD)
#define N_WVW  (DD*DD)
#define N_WVB  (DD)
#define N_WKW  (CC*DD*DD)
#define N_WKB  (CC*DD)
#define N_WOW  (DD*DD)
#define N_WOB  (DD)
#define P0 0
#define P1 (P0+N_X)
#define P2 (P1+N_COND)
#define P3 (P2+N_WQW)
#define P4 (P3+N_WQB)
#define P5 (P4+N_WVW)
#define P6 (P5+N_WVB)
#define P7 (P6+N_WKW)
#define P8 (P7+N_WKB)
#define P9 (P8+N_WOW)
#define PTOT (P9+N_WOB)

// --------------------------------------------------------------------------
__global__ void detect_dtype(const void* x, int* flag)
{
    __shared__ int total;
    if (threadIdx.x == 0) total = 0;
    __syncthreads();
    const float* xf = (const float*)x;
    int cnt = 0;
    for (int i = threadIdx.x; i < 4096; i += 256) {
        float v = fabsf(xf[i]);
        if (v == v && v > 1e-4f && v < 1e4f) cnt++;
    }
    atomicAdd(&total, cnt);
    __syncthreads();
    if (threadIdx.x == 0) *flag = (total > 2048) ? 1 : 0;
}

__global__ void convert_all(const void* s0, const void* s1, const void* s2,
                            const void* s3, const void* s4, const void* s5,
                            const void* s6, const void* s7, const void* s8,
                            const void* s9, bf16* dst, const int* flagp)
{
    const bool f32 = (*flagp != 0);
    size_t i = ((size_t)blockIdx.x * 256 + threadIdx.x) * 8;
    const size_t stride = (size_t)gridDim.x * 256 * 8;
    for (; i < (size_t)PTOT; i += stride) {
        const void* src; size_t off;
        if      (i < P1) { src = s0; off = i - P0; }
        else if (i < P2) { src = s1; off = i - P1; }
        else if (i < P3) { src = s2; off = i - P2; }
        else if (i < P4) { src = s3; off = i - P3; }
        else if (i < P5) { src = s4; off = i - P4; }
        else if (i < P6) { src = s5; off = i - P5; }
        else if (i < P7) { src = s6; off = i - P6; }
        else if (i < P8) { src = s7; off = i - P7; }
        else if (i < P9) { src = s8; off = i - P8; }
        else             { src = s9; off = i - P9; }
        if (f32) {
            const float* s = (const float*)src + off;
            float4 a = *(const float4*)(s);
            float4 b = *(const float4*)(s + 4);
            __align__(16) unsigned short t[8];
            t[0] = f2bfbits(a.x); t[1] = f2bfbits(a.y);
            t[2] = f2bfbits(a.z); t[3] = f2bfbits(a.w);
            t[4] = f2bfbits(b.x); t[5] = f2bfbits(b.y);
            t[6] = f2bfbits(b.z); t[7] = f2bfbits(b.w);
            *(uint4*)(dst + i) = *(const uint4*)t;
        } else {
            *(uint4*)(dst + i) = *(const uint4*)((const unsigned short*)src + off);
        }
    }
}

// ---------------------------------------------------------------------------
// GEMM: Y[m,n] = sum_k X[m,k]*W[n,k] + bias[n].  (unchanged)
// ---------------------------------------------------------------------------
__launch_bounds__(256, 2)
__global__ void gemm_bias(const bf16* __restrict__ X, const bf16* __restrict__ W,
                          const bf16* __restrict__ bias, void* __restrict__ Yv,
                          const int* __restrict__ flagp, int flex_out, int vt_out)
{
    const int LDT = 264;
    __shared__ __align__(16) unsigned short xs[64 * 264];
    __shared__ __align__(16) unsigned short ws[64 * 264];
    const int t  = threadIdx.x;
    const int m0 = blockIdx.y * 64;
    const int n0 = blockIdx.x * 64;

    for (int i = 0; i < 8; ++i) {
        int c = t + i * 256;
        int row = c >> 5, col = (c & 31) * 8;
        *(uint4*)&xs[row * LDT + col] = *(const uint4*)(X + (size_t)(m0 + row) * DD + col);
        *(uint4*)&ws[row * LDT + col] = *(const uint4*)(W + (size_t)(n0 + row) * DD + col);
    }
    __syncthreads();

    const int w = t >> 6, lane = t & 63;
    const int lrow = lane & 15, lk = (lane >> 4) * 8, rgrp = (lane >> 4) * 4;
    floatx4 acc[4] = {};
    const unsigned short* ax = &xs[(w * 16 + lrow) * LDT + lk];
    for (int kt = 0; kt < 8; ++kt) {
        short8 a = *(const short8*)(ax + kt * 32);
        #pragma unroll
        for (int j = 0; j < 4; ++j) {
            short8 b = *(const short8*)&ws[(j * 16 + lrow) * LDT + kt * 32 + lk];
            acc[j] = __builtin_amdgcn_mfma_f32_16x16x32_bf16(a, b, acc[j], 0, 0, 0);
        }
    }

    if (vt_out) {
        __syncthreads();
        unsigned short* ts = xs;
        #pragma unroll
        for (int j = 0; j < 4; ++j) {
            float bv = __bfloat162float(bias[n0 + j * 16 + lrow]);
            #pragma unroll
            for (int r = 0; r < 4; ++r)
                ts[(j * 16 + lrow) * 72 + w * 16 + rgrp + r] = f2bfbits(acc[j][r] + bv);
        }
        __syncthreads();
        const int bq = m0 >> 11, s0v = m0 & 2047, h = n0 >> 6;
        bf16* dstb = (bf16*)Yv + ((size_t)(bq * HH + h) * HD) * SS + s0v;
        for (int i = 0; i < 2; ++i) {
            int idx = t + i * 256, row = idx >> 3, ch = (idx & 7) * 8;
            *(uint4*)(dstb + (size_t)row * SS + ch) = *(const uint4*)&ts[row * 72 + ch];
        }
        return;
    }

    const bool f32o = flex_out && (*flagp != 0);
    #pragma unroll
    for (int j = 0; j < 4; ++j) {
        int col = n0 + j * 16 + lrow;
        float bv = __bfloat162float(bias[col]);
        #pragma unroll
        for (int r = 0; r < 4; ++r) {
            int row = m0 + w * 16 + rgrp + r;
            float val = acc[j][r] + bv;
            if (f32o) ((float*)Yv)[(size_t)row * DD + col] = val;
            else      ((bf16*)Yv)[(size_t)row * DD + col] = __float2bfloat16(val);
        }
    }
}

// ---------------------------------------------------------------------------
// Class-dependent key v4.
// 128 thr / 2 waves; block = 128 rows x 64 cols; each wave computes FOUR
// 16-row m-tiles (64 rows) -> every B-fragment ds_read_b128 feeds 4 MFMAs.
// LDS B-traffic/CU/class: 128 KB (floor ~20 us, below the ~30 us MFMA floor).
// X in registers (xa[4][8] = 128 VGPR), Wk ping-pong via global_load_lds +
// XOR chunk swizzle. ~290 VGPR -> launch_bounds(128,1), 1 wave/SIMD; ILP
// from 16 independent MFMA chains per wave.
// ---------------------------------------------------------------------------
__device__ inline void stage_ws64(const bf16* __restrict__ Wc,
                                  unsigned short* wsbuf, int w, int lane)
{
    #pragma unroll
    for (int i = 0; i < 16; ++i) {
        int rr = w * 32 + i * 2 + (lane >> 5);       // row 0..63 of the slice
        int cs = (lane & 31) ^ (rr & 7);             // swizzled global chunk
        const bf16* src = Wc + (size_t)rr * DD + cs * 8;
        unsigned short* dst = wsbuf + (size_t)(w * 32 + i * 2) * DD;  // wave-uniform
#if HAVE_GLL
        __builtin_amdgcn_global_load_lds(
            (const __attribute__((address_space(1))) void*)src,
            (__attribute__((address_space(3))) void*)dst, 16, 0, 0);
#else
        uint4 v = *(const uint4*)src;
        *(uint4*)(dst + (size_t)lane * 8) = v;
#endif
    }
}

__launch_bounds__(128, 1)
__global__ void classkey(const bf16* __restrict__ X, const bf16* __restrict__ Cond,
                         const bf16* __restrict__ Wk, const bf16* __restrict__ Wkb,
                         bf16* __restrict__ Kout)
{
    __shared__ __align__(16) unsigned short ws[2][64 * 256];   // 64 KB ping-pong
    __shared__ __align__(16) unsigned short conds[128 * 32];   // 8 KB
    __shared__ __align__(16) unsigned short kbs[32 * 64];      // 4 KB
    const int t    = threadIdx.x;
    const int w    = t >> 6;            // wave 0..1
    const int lane = t & 63;
    const int r16  = lane & 15;
    const int quad = lane >> 4;
    const int m0   = blockIdx.y * 128;
    const int n0   = blockIdx.x * 64;

    // cond tile 128x32: 512 uint4 chunks, 4 per thread
    #pragma unroll
    for (int i = 0; i < 4; ++i) {
        int chunk = t + i * 128;
        int row = chunk >> 2, c8 = (chunk & 3) * 8;
        *(uint4*)&conds[row * 32 + c8] = *(const uint4*)(Cond + (size_t)(m0 + row) * CC + c8);
    }
    // Wk_b slice 32x64: 256 uint4 chunks, 2 per thread
    #pragma unroll
    for (int i = 0; i < 2; ++i) {
        int chunk = t + i * 128;
        int row = chunk >> 3, c8 = (chunk & 7) * 8;
        *(uint4*)&kbs[row * 64 + c8] = *(const uint4*)(Wkb + (size_t)row * DD + n0 + c8);
    }

    // X rows for this wave's four m-tiles -> registers
    short8 xa[4][8];
    #pragma unroll
    for (int mt = 0; mt < 4; ++mt) {
        const bf16* xrow = X + (size_t)(m0 + w * 64 + mt * 16 + r16) * DD + quad * 8;
        #pragma unroll
        for (int kt = 0; kt < 8; ++kt)
            xa[mt][kt] = *(const short8*)(xrow + kt * 32);
    }

    stage_ws64(Wk + (size_t)n0 * DD, &ws[0][0], w, lane);

    floatx4 acck[4][4] = {};
    for (int c = 0; c < CC; ++c) {
        __syncthreads();   // vmcnt(0) drain: buf[c&1] staged; buf[(c+1)&1] free
        if (c + 1 < CC)
            stage_ws64(Wk + (size_t)(c + 1) * DD * DD + (size_t)n0 * DD,
                       &ws[(c + 1) & 1][0], w, lane);

        const unsigned short* wb = &ws[c & 1][0];
        floatx4 p[4][4] = {};
        #pragma unroll
        for (int kt = 0; kt < 8; ++kt) {
            short8 bj[4];
            #pragma unroll
            for (int j = 0; j < 4; ++j)
                bj[j] = *(const short8*)&wb[(j * 16 + r16) * DD +
                                            (((kt * 4 + quad) ^ (r16 & 7)) << 3)];
            #pragma unroll
            for (int mt = 0; mt < 4; ++mt)
                #pragma unroll
                for (int j = 0; j < 4; ++j)
                    p[mt][j] = __builtin_amdgcn_mfma_f32_16x16x32_bf16(xa[mt][kt], bj[j], p[mt][j], 0, 0, 0);
        }
        #pragma unroll
        for (int mt = 0; mt < 4; ++mt)
            #pragma unroll
            for (int r = 0; r < 4; ++r) {
                float cv = bf2f(conds[(w * 64 + mt * 16 + quad * 4 + r) * 32 + c]);
                #pragma unroll
                for (int j = 0; j < 4; ++j) acck[mt][j][r] += cv * p[mt][j][r];
            }
    }

    // bias: sum_c cond[row,c] * Wkb[c,col]
    float kbv[4][4];
    #pragma unroll
    for (int mt = 0; mt < 4; ++mt)
        #pragma unroll
        for (int j = 0; j < 4; ++j) kbv[mt][j] = 0.f;
    for (int c = 0; c < CC; ++c) {
        #pragma unroll
        for (int mt = 0; mt < 4; ++mt) {
            // accumulate per (mt, j) with the r-dependence folded at write time
            // kbv needs per-r cond; handle below instead
        }
        break;
    }
    // (per-r bias accumulation, done explicitly to keep registers bounded)
    #pragma unroll
    for (int mt = 0; mt < 4; ++mt) {
        float kb_r[4][4] = {};   // [j][r]
        for (int c = 0; c < CC; ++c) {
            #pragma unroll
            for (int r = 0; r < 4; ++r) {
                float cf = bf2f(conds[(w * 64 + mt * 16 + quad * 4 + r) * 32 + c]);
                #pragma unroll
                for (int j = 0; j < 4; ++j)
                    kb_r[j][r] += cf * bf2f(kbs[c * 64 + j * 16 + r16]);
            }
        }
        #pragma unroll
        for (int j = 0; j < 4; ++j) {
            int col = n0 + j * 16 + r16;
            #pragma unroll
            for (int r = 0; r < 4; ++r) {
                int row = m0 + w * 64 + mt * 16 + quad * 4 + r;
                Kout[(size_t)row * DD + col] = __float2bfloat16(acck[mt][j][r] + kb_r[j][r]);
            }
        }
    }
}

// ---------------------------------------------------------------------------
// Flash attention v2 (unchanged from R5 — validated).
// ---------------------------------------------------------------------------
__device__ inline void stage_kv(const bf16* __restrict__ kRow,
                                const bf16* __restrict__ vRow,
                                unsigned short* kbuf, unsigned short* vbuf,
                                int w, int lane)
{
    int r  = w * 8 + (lane >> 3);
    int cs = (lane & 7) ^ (r & 7);
#if HAVE_GLL
    __builtin_amdgcn_global_load_lds(
        (const __attribute__((address_space(1))) void*)(kRow + (size_t)r * DD + cs * 8),
        (__attribute__((address_space(3))) void*)(kbuf + w * 512), 16, 0, 0);
    __builtin_amdgcn_global_load_lds(
        (const __attribute__((address_space(1))) void*)(vRow + (size_t)r * SS + cs * 8),
        (__attribute__((address_space(3))) void*)(vbuf + w * 512), 16, 0, 0);
#else
    *(uint4*)(kbuf + w * 512 + (size_t)lane * 8) = *(const uint4*)(kRow + (size_t)r * DD + cs * 8);
    *(uint4*)(vbuf + w * 512 + (size_t)lane * 8) = *(const uint4*)(vRow + (size_t)r * SS + cs * 8);
#endif
}

__launch_bounds__(512, 4)
__global__ void attn(const bf16* __restrict__ Q, const bf16* __restrict__ Kb,
                     const bf16* __restrict__ VT, bf16* __restrict__ O)
{
    __shared__ __align__(16) unsigned short ks[2][64 * 64];
    __shared__ __align__(16) unsigned short vt[2][64 * 64];
#if !HAVE_PV16
    __shared__ __align__(16) unsigned short ps[128 * 72];
#endif
    const int t    = threadIdx.x;
    const int w    = t >> 6;
    const int lane = t & 63;
    const int r16  = lane & 15;
    const int quad = lane >> 4;
    const int bh   = blockIdx.y;
    const int b    = bh >> 2, h = bh & 3;
    const int q0   = blockIdx.x * 128;
    const size_t base  = ((size_t)b * SS) * DD + h * HD;
    const size_t vbase = (size_t)bh * HD * SS;

    short8 qa[2];
    {
        const bf16* qrow = Q + base + (size_t)(q0 + w * 16 + r16) * DD + quad * 8;
        #pragma unroll
        for (int k2 = 0; k2 < 2; ++k2) {
            short8 raw = *(const short8*)(qrow + k2 * 32);
            short8 sc;
            #pragma unroll
            for (int e = 0; e < 8; ++e)
                sc[e] = (short)f2bfbits(bf2f((unsigned short)raw[e]) * 0.125f);
            qa[k2] = sc;
        }
    }

    stage_kv(Kb + base, VT + vbase, &ks[0][0], &vt[0][0], w, lane);

    floatx4 acco[4] = {};
    float mrun = -1e30f, lrun = 0.f;

    for (int kt = 0; kt < SS / 64; ++kt) {
        __syncthreads();
        if (kt + 1 < SS / 64)
            stage_kv(Kb + base + (size_t)(kt + 1) * 64 * DD,
                     VT + vbase + (size_t)(kt + 1) * 64,
                     &ks[(kt + 1) & 1][0], &vt[(kt + 1) & 1][0], w, lane);

        const unsigned short* kbuf = &ks[kt & 1][0];
        const unsigned short* vbuf = &vt[kt & 1][0];

        floatx4 s[4] = {};
        #pragma unroll
        for (int k2 = 0; k2 < 2; ++k2) {
            short8 bq = qa[k2];
            #pragma unroll
            for (int j = 0; j < 4; ++j) {
                short8 ak = *(const short8*)&kbuf[(j * 16 + r16) * 64 +
                                                  (((k2 * 4 + quad) ^ (r16 & 7)) << 3)];
                s[j] = __builtin_amdgcn_mfma_f32_16x16x32_bf16(ak, bq, s[j], 0, 0, 0);
            }
        }

        float mx = -1e30f;
        #pragma unroll
        for (int j = 0; j < 4; ++j)
            #pragma unroll
            for (int r = 0; r < 4; ++r) mx = fmaxf(mx, s[j][r]);
        mx = fmaxf(mx, __shfl_xor(mx, 16, 64));
        mx = fmaxf(mx, __shfl_xor(mx, 32, 64));
        float mnew  = fmaxf(mrun, mx);
        float alpha = __expf(mrun - mnew);
        float sum = 0.f;
        #pragma unroll
        for (int j = 0; j < 4; ++j)
            #pragma unroll
            for (int r = 0; r < 4; ++r) {
                float e = __expf(s[j][r] - mnew);
                s[j][r] = e; sum += e;
            }
        sum += __shfl_xor(sum, 16, 64);
        sum += __shfl_xor(sum, 32, 64);
        lrun = lrun * alpha + sum;
        mrun = mnew;

        #pragma unroll
        for (int r = 0; r < 4; ++r) {
            float ar = __shfl(alpha, (quad << 4) + quad * 4 + r, 64);
            #pragma unroll
            for (int jn = 0; jn < 4; ++jn) acco[jn][r] *= ar;
        }

#if HAVE_PV16
        #pragma unroll
        for (int j = 0; j < 4; ++j) {
            short4v p;
            p[0] = (short)f2bfbits(s[j][0]); p[1] = (short)f2bfbits(s[j][1]);
            p[2] = (short)f2bfbits(s[j][2]); p[3] = (short)f2bfbits(s[j][3]);
            #pragma unroll
            for (int jn = 0; jn < 4; ++jn) {
                short4v vv = *(const short4v*)&vbuf[(jn * 16 + r16) * 64 +
                                                    ((((j * 2) + (quad >> 1)) ^ (r16 & 7)) << 3) +
                                                    (quad & 1) * 4];
                acco[jn] = MFMA_PV16(p, vv, acco[jn]);
            }
        }
#else
        #pragma unroll
        for (int j = 0; j < 4; ++j)
            #pragma unroll
            for (int r = 0; r < 4; ++r)
                ps[(w * 16 + r16) * 72 + j * 16 + quad * 4 + r] = f2bfbits(s[j][r]);
        #pragma unroll
        for (int k2 = 0; k2 < 2; ++k2) {
            short8 a = *(const short8*)&ps[(w * 16 + r16) * 72 + k2 * 32 + quad * 8];
            #pragma unroll
            for (int jn = 0; jn < 4; ++jn) {
                short8 bb = *(const short8*)&vbuf[(jn * 16 + r16) * 64 +
                                                  (((k2 * 4 + quad) ^ (r16 & 7)) << 3)];
                acco[jn] = __builtin_amdgcn_mfma_f32_16x16x32_bf16(a, bb, acco[jn], 0, 0, 0);
            }
        }
#endif
    }

    #pragma unroll
    for (int r = 0; r < 4; ++r) {
        float lr = __shfl(lrun, (quad << 4) + quad * 4 + r, 64);
        float inv = 1.0f / lr;
        int row = q0 + w * 16 + quad * 4 + r;
        #pragma unroll
        for (int jn = 0; jn < 4; ++jn)
            O[base + (size_t)row * DD + jn * 16 + r16] = __float2bfloat16(acco[jn][r] * inv);
    }
}

// ---------------------------------------------------------------------------
extern "C" void kernel_launch(void* const* d_in, const int* in_sizes, int n_in,
                              void* d_out, int out_size, void* d_ws, size_t ws_size,
                              hipStream_t stream)
{
    int*  flag = (int*)d_ws;
    bf16* conv = (bf16*)((char*)d_ws + 256);

    const bf16* xb    = conv + P0;
    const bf16* condb = conv + P1;
    const bf16* wqw   = conv + P2;
    const bf16* wqb   = conv + P3;
    const bf16* wvw   = conv + P4;
    const bf16* wvb   = conv + P5;
    const bf16* wkw   = conv + P6;
    const bf16* wkb   = conv + P7;
    const bf16* wow   = conv + P8;
    const bf16* wob   = conv + P9;

    bf16* qb = conv + PTOT;
    bf16* kb = qb + (size_t)MTOT * DD;
    bf16* vb = kb + (size_t)MTOT * DD;   // V^T layout [b*H+h][hd][S]
    bf16* ob = vb + (size_t)MTOT * DD;

    dim3 blk(256);
    hipLaunchKernelGGL(detect_dtype, dim3(1), blk, 0, stream, d_in[0], flag);
    hipLaunchKernelGGL(convert_all, dim3((PTOT / 8 + 255) / 256), blk, 0, stream,
                       d_in[0], d_in[1], d_in[2], d_in[3], d_in[4],
                       d_in[5], d_in[6], d_in[7], d_in[8], d_in[9],
                       conv, flag);

    dim3 gg(DD / 64, MTOT / 64);
    hipLaunchKernelGGL(gemm_bias, gg, blk, 0, stream, xb, wqw, wqb, (void*)qb, flag, 0, 0);
    hipLaunchKernelGGL(gemm_bias, gg, blk, 0, stream, xb, wvw, wvb, (void*)vb, flag, 0, 1);
    dim3 gck(DD / 64, MTOT / 128);       // (4, 128), 128-thread blocks
    hipLaunchKernelGGL(classkey, gck, dim3(128), 0, stream, xb, condb, wkw, wkb, kb);
    dim3 ga(SS / 128, BB * HH);          // (16, 32), 512-thread blocks
    hipLaunchKernelGGL(attn, ga, dim3(512), 0, stream, qb, kb, vb, ob);
    hipLaunchKernelGGL(gemm_bias, gg, blk, 0, stream, ob, wow, wob, d_out, flag, 1, 0);
}

// Round 8
// 273.913 us; speedup vs baseline: 1.0844x; 1.0844x over previous
//
#include <hip/hip_runtime.h>
#include <hip/hip_bf16.h>

#define BB 8
#define SS 2048
#define DD 256
#define CC 32
#define HH 4
#define HD 64
#define MTOT (BB*SS)   // 16384 tokens

using bf16    = __hip_bfloat16;
using short8  = __attribute__((ext_vector_type(8))) short;
using short4v = __attribute__((ext_vector_type(4))) short;
using floatx4 = __attribute__((ext_vector_type(4))) float;

#if __has_builtin(__builtin_amdgcn_mfma_f32_16x16x16_bf16)
  #define MFMA_PV16(a,b,c) __builtin_amdgcn_mfma_f32_16x16x16_bf16(a,b,c,0,0,0)
  #define HAVE_PV16 1
#elif __has_builtin(__builtin_amdgcn_mfma_f32_16x16x16bf16_1k)
  #define MFMA_PV16(a,b,c) __builtin_amdgcn_mfma_f32_16x16x16bf16_1k(a,b,c,0,0,0)
  #define HAVE_PV16 1
#else
  #define HAVE_PV16 0
#endif

#if __has_builtin(__builtin_amdgcn_global_load_lds)
  #define HAVE_GLL 1
#else
  #define HAVE_GLL 0
#endif

__device__ inline float bf2f(unsigned short u) {
    union { unsigned int i; float f; } v; v.i = ((unsigned int)u) << 16; return v.f;
}
__device__ inline unsigned short f2bfbits(float f) {
    bf16 h = __float2bfloat16(f);
    return __builtin_bit_cast(unsigned short, h);
}

// --------------------------------------------------------------------------
#define N_X    (MTOT*DD)
#define N_COND (MTOT*CC)
#define N_WQW  (DD*DD)
#define N_WQB  (DD)
#define N_WVW  (DD*DD)
#define N_WVB  (DD)
#define N_WKW  (CC*DD*DD)
#define N_WKB  (CC*DD)
#define N_WOW  (DD*DD)
#define N_WOB  (DD)
#define P0 0
#define P1 (P0+N_X)
#define P2 (P1+N_COND)
#define P3 (P2+N_WQW)
#define P4 (P3+N_WQB)
#define P5 (P4+N_WVW)
#define P6 (P5+N_WVB)
#define P7 (P6+N_WKW)
#define P8 (P7+N_WKB)
#define P9 (P8+N_WOW)
#define PTOT (P9+N_WOB)

// --------------------------------------------------------------------------
__global__ void detect_dtype(const void* x, int* flag)
{
    __shared__ int total;
    if (threadIdx.x == 0) total = 0;
    __syncthreads();
    const float* xf = (const float*)x;
    int cnt = 0;
    for (int i = threadIdx.x; i < 4096; i += 256) {
        float v = fabsf(xf[i]);
        if (v == v && v > 1e-4f && v < 1e4f) cnt++;
    }
    atomicAdd(&total, cnt);
    __syncthreads();
    if (threadIdx.x == 0) *flag = (total > 2048) ? 1 : 0;
}

__global__ void convert_all(const void* s0, const void* s1, const void* s2,
                            const void* s3, const void* s4, const void* s5,
                            const void* s6, const void* s7, const void* s8,
                            const void* s9, bf16* dst, const int* flagp)
{
    const bool f32 = (*flagp != 0);
    size_t i = ((size_t)blockIdx.x * 256 + threadIdx.x) * 8;
    const size_t stride = (size_t)gridDim.x * 256 * 8;
    for (; i < (size_t)PTOT; i += stride) {
        const void* src; size_t off;
        if      (i < P1) { src = s0; off = i - P0; }
        else if (i < P2) { src = s1; off = i - P1; }
        else if (i < P3) { src = s2; off = i - P2; }
        else if (i < P4) { src = s3; off = i - P3; }
        else if (i < P5) { src = s4; off = i - P4; }
        else if (i < P6) { src = s5; off = i - P5; }
        else if (i < P7) { src = s6; off = i - P6; }
        else if (i < P8) { src = s7; off = i - P7; }
        else if (i < P9) { src = s8; off = i - P8; }
        else             { src = s9; off = i - P9; }
        if (f32) {
            const float* s = (const float*)src + off;
            float4 a = *(const float4*)(s);
            float4 b = *(const float4*)(s + 4);
            __align__(16) unsigned short t[8];
            t[0] = f2bfbits(a.x); t[1] = f2bfbits(a.y);
            t[2] = f2bfbits(a.z); t[3] = f2bfbits(a.w);
            t[4] = f2bfbits(b.x); t[5] = f2bfbits(b.y);
            t[6] = f2bfbits(b.z); t[7] = f2bfbits(b.w);
            *(uint4*)(dst + i) = *(const uint4*)t;
        } else {
            *(uint4*)(dst + i) = *(const uint4*)((const unsigned short*)src + off);
        }
    }
}

// ---------------------------------------------------------------------------
// GEMM body (R3-validated): Y[m,n] = sum_k X[m,k]*W[n,k] + bias[n].
// Uses first 33792 shorts of smem. 256 threads.
// ---------------------------------------------------------------------------
__device__ __forceinline__ void gemm_body(const bf16* __restrict__ X, const bf16* __restrict__ W,
                                          const bf16* __restrict__ bias, void* __restrict__ Yv,
                                          const int* __restrict__ flagp, int flex_out, int vt_out,
                                          unsigned short* smem, int m0, int n0)
{
    const int LDT = 264;
    unsigned short* xs = smem;
    unsigned short* ws = smem + 64 * 264;
    const int t = threadIdx.x;

    for (int i = 0; i < 8; ++i) {
        int c = t + i * 256;
        int row = c >> 5, col = (c & 31) * 8;
        *(uint4*)&xs[row * LDT + col] = *(const uint4*)(X + (size_t)(m0 + row) * DD + col);
        *(uint4*)&ws[row * LDT + col] = *(const uint4*)(W + (size_t)(n0 + row) * DD + col);
    }
    __syncthreads();

    const int w = t >> 6, lane = t & 63;
    const int lrow = lane & 15, lk = (lane >> 4) * 8, rgrp = (lane >> 4) * 4;
    floatx4 acc[4] = {};
    const unsigned short* ax = &xs[(w * 16 + lrow) * LDT + lk];
    for (int kt = 0; kt < 8; ++kt) {
        short8 a = *(const short8*)(ax + kt * 32);
        #pragma unroll
        for (int j = 0; j < 4; ++j) {
            short8 b = *(const short8*)&ws[(j * 16 + lrow) * LDT + kt * 32 + lk];
            acc[j] = __builtin_amdgcn_mfma_f32_16x16x32_bf16(a, b, acc[j], 0, 0, 0);
        }
    }

    if (vt_out) {
        __syncthreads();
        unsigned short* ts = xs;
        #pragma unroll
        for (int j = 0; j < 4; ++j) {
            float bv = __bfloat162float(bias[n0 + j * 16 + lrow]);
            #pragma unroll
            for (int r = 0; r < 4; ++r)
                ts[(j * 16 + lrow) * 72 + w * 16 + rgrp + r] = f2bfbits(acc[j][r] + bv);
        }
        __syncthreads();
        const int bq = m0 >> 11, s0v = m0 & 2047, h = n0 >> 6;
        bf16* dstb = (bf16*)Yv + ((size_t)(bq * HH + h) * HD) * SS + s0v;
        for (int i = 0; i < 2; ++i) {
            int idx = t + i * 256, row = idx >> 3, ch = (idx & 7) * 8;
            *(uint4*)(dstb + (size_t)row * SS + ch) = *(const uint4*)&ts[row * 72 + ch];
        }
        return;
    }

    const bool f32o = flex_out && (*flagp != 0);
    #pragma unroll
    for (int j = 0; j < 4; ++j) {
        int col = n0 + j * 16 + lrow;
        float bv = __bfloat162float(bias[col]);
        #pragma unroll
        for (int r = 0; r < 4; ++r) {
            int row = m0 + w * 16 + rgrp + r;
            float val = acc[j][r] + bv;
            if (f32o) ((float*)Yv)[(size_t)row * DD + col] = val;
            else      ((bf16*)Yv)[(size_t)row * DD + col] = __float2bfloat16(val);
        }
    }
}

// ---------------------------------------------------------------------------
// classkey body — EXACT R6 structure (validated 78 us): 256 thr / 4 waves,
// 128 rows x 64 cols, 2 m-tiles per wave, X in registers, Wk ping-pong via
// global_load_lds + XOR chunk swizzle.
// smem layout: ws[2][64*256] (32768) | conds[128*32] (4096) | kbs[32*64] (2048)
// ---------------------------------------------------------------------------
__device__ __forceinline__ void stage_ws4(const bf16* __restrict__ Wc,
                                          unsigned short* wsbuf, int w, int lane)
{
    #pragma unroll
    for (int i = 0; i < 8; ++i) {
        int rr = w * 16 + i * 2 + (lane >> 5);
        int cs = (lane & 31) ^ (rr & 7);
        const bf16* src = Wc + (size_t)rr * DD + cs * 8;
        unsigned short* dst = wsbuf + (size_t)(w * 16 + i * 2) * DD;
#if HAVE_GLL
        __builtin_amdgcn_global_load_lds(
            (const __attribute__((address_space(1))) void*)src,
            (__attribute__((address_space(3))) void*)dst, 16, 0, 0);
#else
        uint4 v = *(const uint4*)src;
        *(uint4*)(dst + (size_t)lane * 8) = v;
#endif
    }
}

__device__ __forceinline__ void classkey_body(const bf16* __restrict__ X, const bf16* __restrict__ Cond,
                                              const bf16* __restrict__ Wk, const bf16* __restrict__ Wkb,
                                              bf16* __restrict__ Kout,
                                              unsigned short* smem, int m0, int n0)
{
    unsigned short* ws0   = smem;                 // ws[0]
    unsigned short* ws1   = smem + 64 * 256;      // ws[1]
    unsigned short* conds = smem + 2 * 64 * 256;  // 128*32
    unsigned short* kbs   = conds + 128 * 32;     // 32*64
    const int t    = threadIdx.x;
    const int w    = t >> 6;
    const int lane = t & 63;
    const int r16  = lane & 15;
    const int quad = lane >> 4;

    #pragma unroll
    for (int i = 0; i < 2; ++i) {
        int chunk = t + i * 256;
        int row = chunk >> 2, c8 = (chunk & 3) * 8;
        *(uint4*)&conds[row * 32 + c8] = *(const uint4*)(Cond + (size_t)(m0 + row) * CC + c8);
    }
    {
        int row = t >> 3, c8 = (t & 7) * 8;
        *(uint4*)&kbs[row * 64 + c8] = *(const uint4*)(Wkb + (size_t)row * DD + n0 + c8);
    }

    short8 xa[2][8];
    #pragma unroll
    for (int mt = 0; mt < 2; ++mt) {
        const bf16* xrow = X + (size_t)(m0 + w * 32 + mt * 16 + r16) * DD + quad * 8;
        #pragma unroll
        for (int kt = 0; kt < 8; ++kt)
            xa[mt][kt] = *(const short8*)(xrow + kt * 32);
    }

    stage_ws4(Wk + (size_t)n0 * DD, ws0, w, lane);

    floatx4 acck[2][4] = {};
    for (int c = 0; c < CC; ++c) {
        __syncthreads();
        if (c + 1 < CC)
            stage_ws4(Wk + (size_t)(c + 1) * DD * DD + (size_t)n0 * DD,
                      ((c + 1) & 1) ? ws1 : ws0, w, lane);

        const unsigned short* wb = (c & 1) ? ws1 : ws0;
        floatx4 p[2][4] = {};
        #pragma unroll
        for (int kt = 0; kt < 8; ++kt) {
            short8 bj[4];
            #pragma unroll
            for (int j = 0; j < 4; ++j)
                bj[j] = *(const short8*)&wb[(j * 16 + r16) * DD +
                                            (((kt * 4 + quad) ^ (r16 & 7)) << 3)];
            #pragma unroll
            for (int mt = 0; mt < 2; ++mt)
                #pragma unroll
                for (int j = 0; j < 4; ++j)
                    p[mt][j] = __builtin_amdgcn_mfma_f32_16x16x32_bf16(xa[mt][kt], bj[j], p[mt][j], 0, 0, 0);
        }
        #pragma unroll
        for (int mt = 0; mt < 2; ++mt)
            #pragma unroll
            for (int r = 0; r < 4; ++r) {
                float cv = bf2f(conds[(w * 32 + mt * 16 + quad * 4 + r) * 32 + c]);
                #pragma unroll
                for (int j = 0; j < 4; ++j) acck[mt][j][r] += cv * p[mt][j][r];
            }
    }

    float kbv[2][4][4] = {};
    for (int c = 0; c < CC; ++c) {
        #pragma unroll
        for (int mt = 0; mt < 2; ++mt)
            #pragma unroll
            for (int r = 0; r < 4; ++r) {
                float cf = bf2f(conds[(w * 32 + mt * 16 + quad * 4 + r) * 32 + c]);
                #pragma unroll
                for (int j = 0; j < 4; ++j)
                    kbv[mt][j][r] += cf * bf2f(kbs[c * 64 + j * 16 + r16]);
            }
    }
    #pragma unroll
    for (int mt = 0; mt < 2; ++mt)
        #pragma unroll
        for (int j = 0; j < 4; ++j) {
            int col = n0 + j * 16 + r16;
            #pragma unroll
            for (int r = 0; r < 4; ++r) {
                int row = m0 + w * 32 + mt * 16 + quad * 4 + r;
                Kout[(size_t)row * DD + col] = __float2bfloat16(acck[mt][j][r] + kbv[mt][j][r]);
            }
        }
}

// ---------------------------------------------------------------------------
// Fused dispatch: classkey (512 blocks) + Q-proj (1024) + V-proj (1024),
// interleaved [ck,g,g,g,g] so each CU hosts a mix — gemm waves fill
// classkey's stall cycles (all roles independent; G16-safe).
// LDS: union, classkey layout (77824 B) is the superset.
// ---------------------------------------------------------------------------
__launch_bounds__(256, 2)
__global__ void fused_qvk(const bf16* __restrict__ X, const bf16* __restrict__ Cond,
                          const bf16* __restrict__ Wk, const bf16* __restrict__ Wkb,
                          bf16* __restrict__ Kout,
                          const bf16* __restrict__ Wqw, const bf16* __restrict__ Wqb, bf16* __restrict__ Qout,
                          const bf16* __restrict__ Wvw, const bf16* __restrict__ Wvb, bf16* __restrict__ Vout,
                          const int* __restrict__ flagp)
{
    __shared__ __align__(16) unsigned short smem[2 * 64 * 256 + 128 * 32 + 32 * 64];
    const int bid = blockIdx.x;
    const int grp = bid / 5, rem = bid % 5;
    if (rem == 0) {
        // classkey block grp in 0..511: grid was (4 n, 128 m)
        int n0 = (grp & 3) * 64, m0 = (grp >> 2) * 128;
        classkey_body(X, Cond, Wk, Wkb, Kout, smem, m0, n0);
    } else {
        int gi = grp * 4 + (rem - 1);      // 0..2047
        if (gi < 1024) {
            int n0 = (gi & 3) * 64, m0 = (gi >> 2) * 64;
            gemm_body(X, Wqw, Wqb, (void*)Qout, flagp, 0, 0, smem, m0, n0);
        } else {
            gi -= 1024;
            int n0 = (gi & 3) * 64, m0 = (gi >> 2) * 64;
            gemm_body(X, Wvw, Wvb, (void*)Vout, flagp, 0, 1, smem, m0, n0);
        }
    }
}

// standalone gemm for the output projection
__launch_bounds__(256, 2)
__global__ void gemm_bias(const bf16* __restrict__ X, const bf16* __restrict__ W,
                          const bf16* __restrict__ bias, void* __restrict__ Yv,
                          const int* __restrict__ flagp, int flex_out, int vt_out)
{
    __shared__ __align__(16) unsigned short smem[2 * 64 * 264];
    gemm_body(X, W, bias, Yv, flagp, flex_out, vt_out, smem, blockIdx.y * 64, blockIdx.x * 64);
}

// ---------------------------------------------------------------------------
// Flash attention v2 (unchanged from R5 — validated).
// ---------------------------------------------------------------------------
__device__ inline void stage_kv(const bf16* __restrict__ kRow,
                                const bf16* __restrict__ vRow,
                                unsigned short* kbuf, unsigned short* vbuf,
                                int w, int lane)
{
    int r  = w * 8 + (lane >> 3);
    int cs = (lane & 7) ^ (r & 7);
#if HAVE_GLL
    __builtin_amdgcn_global_load_lds(
        (const __attribute__((address_space(1))) void*)(kRow + (size_t)r * DD + cs * 8),
        (__attribute__((address_space(3))) void*)(kbuf + w * 512), 16, 0, 0);
    __builtin_amdgcn_global_load_lds(
        (const __attribute__((address_space(1))) void*)(vRow + (size_t)r * SS + cs * 8),
        (__attribute__((address_space(3))) void*)(vbuf + w * 512), 16, 0, 0);
#else
    *(uint4*)(kbuf + w * 512 + (size_t)lane * 8) = *(const uint4*)(kRow + (size_t)r * DD + cs * 8);
    *(uint4*)(vbuf + w * 512 + (size_t)lane * 8) = *(const uint4*)(vRow + (size_t)r * SS + cs * 8);
#endif
}

__launch_bounds__(512, 4)
__global__ void attn(const bf16* __restrict__ Q, const bf16* __restrict__ Kb,
                     const bf16* __restrict__ VT, bf16* __restrict__ O)
{
    __shared__ __align__(16) unsigned short ks[2][64 * 64];
    __shared__ __align__(16) unsigned short vt[2][64 * 64];
#if !HAVE_PV16
    __shared__ __align__(16) unsigned short ps[128 * 72];
#endif
    const int t    = threadIdx.x;
    const int w    = t >> 6;
    const int lane = t & 63;
    const int r16  = lane & 15;
    const int quad = lane >> 4;
    const int bh   = blockIdx.y;
    const int b    = bh >> 2, h = bh & 3;
    const int q0   = blockIdx.x * 128;
    const size_t base  = ((size_t)b * SS) * DD + h * HD;
    const size_t vbase = (size_t)bh * HD * SS;

    short8 qa[2];
    {
        const bf16* qrow = Q + base + (size_t)(q0 + w * 16 + r16) * DD + quad * 8;
        #pragma unroll
        for (int k2 = 0; k2 < 2; ++k2) {
            short8 raw = *(const short8*)(qrow + k2 * 32);
            short8 sc;
            #pragma unroll
            for (int e = 0; e < 8; ++e)
                sc[e] = (short)f2bfbits(bf2f((unsigned short)raw[e]) * 0.125f);
            qa[k2] = sc;
        }
    }

    stage_kv(Kb + base, VT + vbase, &ks[0][0], &vt[0][0], w, lane);

    floatx4 acco[4] = {};
    float mrun = -1e30f, lrun = 0.f;

    for (int kt = 0; kt < SS / 64; ++kt) {
        __syncthreads();
        if (kt + 1 < SS / 64)
            stage_kv(Kb + base + (size_t)(kt + 1) * 64 * DD,
                     VT + vbase + (size_t)(kt + 1) * 64,
                     &ks[(kt + 1) & 1][0], &vt[(kt + 1) & 1][0], w, lane);

        const unsigned short* kbuf = &ks[kt & 1][0];
        const unsigned short* vbuf = &vt[kt & 1][0];

        floatx4 s[4] = {};
        #pragma unroll
        for (int k2 = 0; k2 < 2; ++k2) {
            short8 bq = qa[k2];
            #pragma unroll
            for (int j = 0; j < 4; ++j) {
                short8 ak = *(const short8*)&kbuf[(j * 16 + r16) * 64 +
                                                  (((k2 * 4 + quad) ^ (r16 & 7)) << 3)];
                s[j] = __builtin_amdgcn_mfma_f32_16x16x32_bf16(ak, bq, s[j], 0, 0, 0);
            }
        }

        float mx = -1e30f;
        #pragma unroll
        for (int j = 0; j < 4; ++j)
            #pragma unroll
            for (int r = 0; r < 4; ++r) mx = fmaxf(mx, s[j][r]);
        mx = fmaxf(mx, __shfl_xor(mx, 16, 64));
        mx = fmaxf(mx, __shfl_xor(mx, 32, 64));
        float mnew  = fmaxf(mrun, mx);
        float alpha = __expf(mrun - mnew);
        float sum = 0.f;
        #pragma unroll
        for (int j = 0; j < 4; ++j)
            #pragma unroll
            for (int r = 0; r < 4; ++r) {
                float e = __expf(s[j][r] - mnew);
                s[j][r] = e; sum += e;
            }
        sum += __shfl_xor(sum, 16, 64);
        sum += __shfl_xor(sum, 32, 64);
        lrun = lrun * alpha + sum;
        mrun = mnew;

        #pragma unroll
        for (int r = 0; r < 4; ++r) {
            float ar = __shfl(alpha, (quad << 4) + quad * 4 + r, 64);
            #pragma unroll
            for (int jn = 0; jn < 4; ++jn) acco[jn][r] *= ar;
        }

#if HAVE_PV16
        #pragma unroll
        for (int j = 0; j < 4; ++j) {
            short4v p;
            p[0] = (short)f2bfbits(s[j][0]); p[1] = (short)f2bfbits(s[j][1]);
            p[2] = (short)f2bfbits(s[j][2]); p[3] = (short)f2bfbits(s[j][3]);
            #pragma unroll
            for (int jn = 0; jn < 4; ++jn) {
                short4v vv = *(const short4v*)&vbuf[(jn * 16 + r16) * 64 +
                                                    ((((j * 2) + (quad >> 1)) ^ (r16 & 7)) << 3) +
                                                    (quad & 1) * 4];
                acco[jn] = MFMA_PV16(p, vv, acco[jn]);
            }
        }
#else
        #pragma unroll
        for (int j = 0; j < 4; ++j)
            #pragma unroll
            for (int r = 0; r < 4; ++r)
                ps[(w * 16 + r16) * 72 + j * 16 + quad * 4 + r] = f2bfbits(s[j][r]);
        #pragma unroll
        for (int k2 = 0; k2 < 2; ++k2) {
            short8 a = *(const short8*)&ps[(w * 16 + r16) * 72 + k2 * 32 + quad * 8];
            #pragma unroll
            for (int jn = 0; jn < 4; ++jn) {
                short8 bb = *(const short8*)&vbuf[(jn * 16 + r16) * 64 +
                                                  (((k2 * 4 + quad) ^ (r16 & 7)) << 3)];
                acco[jn] = __builtin_amdgcn_mfma_f32_16x16x32_bf16(a, bb, acco[jn], 0, 0, 0);
            }
        }
#endif
    }

    #pragma unroll
    for (int r = 0; r < 4; ++r) {
        float lr = __shfl(lrun, (quad << 4) + quad * 4 + r, 64);
        float inv = 1.0f / lr;
        int row = q0 + w * 16 + quad * 4 + r;
        #pragma unroll
        for (int jn = 0; jn < 4; ++jn)
            O[base + (size_t)row * DD + jn * 16 + r16] = __float2bfloat16(acco[jn][r] * inv);
    }
}

// ---------------------------------------------------------------------------
extern "C" void kernel_launch(void* const* d_in, const int* in_sizes, int n_in,
                              void* d_out, int out_size, void* d_ws, size_t ws_size,
                              hipStream_t stream)
{
    int*  flag = (int*)d_ws;
    bf16* conv = (bf16*)((char*)d_ws + 256);

    const bf16* xb    = conv + P0;
    const bf16* condb = conv + P1;
    const bf16* wqw   = conv + P2;
    const bf16* wqb   = conv + P3;
    const bf16* wvw   = conv + P4;
    const bf16* wvb   = conv + P5;
    const bf16* wkw   = conv + P6;
    const bf16* wkb   = conv + P7;
    const bf16* wow   = conv + P8;
    const bf16* wob   = conv + P9;

    bf16* qb = conv + PTOT;
    bf16* kb = qb + (size_t)MTOT * DD;
    bf16* vb = kb + (size_t)MTOT * DD;   // V^T layout [b*H+h][hd][S]
    bf16* ob = vb + (size_t)MTOT * DD;

    dim3 blk(256);
    hipLaunchKernelGGL(detect_dtype, dim3(1), blk, 0, stream, d_in[0], flag);
    hipLaunchKernelGGL(convert_all, dim3((PTOT / 8 + 255) / 256), blk, 0, stream,
                       d_in[0], d_in[1], d_in[2], d_in[3], d_in[4],
                       d_in[5], d_in[6], d_in[7], d_in[8], d_in[9],
                       conv, flag);

    // fused: classkey (512) + Q-proj (1024) + V-proj (1024), interleaved 1:4
    hipLaunchKernelGGL(fused_qvk, dim3(2560), blk, 0, stream,
                       xb, condb, wkw, wkb, kb,
                       wqw, wqb, qb, wvw, wvb, vb, flag);

    dim3 ga(SS / 128, BB * HH);          // (16, 32), 512-thread blocks
    hipLaunchKernelGGL(attn, ga, dim3(512), 0, stream, qb, kb, vb, ob);

    dim3 gg(DD / 64, MTOT / 64);
    hipLaunchKernelGGL(gemm_bias, gg, blk, 0, stream, ob, wow, wob, d_out, flag, 1, 0);
}

// Round 9
// 251.131 us; speedup vs baseline: 1.1827x; 1.0907x over previous
//
#include <hip/hip_runtime.h>
#include <hip/hip_bf16.h>

#define BB 8
#define SS 2048
#define DD 256
#define CC 32
#define HH 4
#define HD 64
#define MTOT (BB*SS)   // 16384 tokens

using bf16    = __hip_bfloat16;
using short8  = __attribute__((ext_vector_type(8))) short;
using short4v = __attribute__((ext_vector_type(4))) short;
using floatx4 = __attribute__((ext_vector_type(4))) float;

#if __has_builtin(__builtin_amdgcn_mfma_f32_16x16x16_bf16)
  #define MFMA_PV16(a,b,c) __builtin_amdgcn_mfma_f32_16x16x16_bf16(a,b,c,0,0,0)
  #define HAVE_PV16 1
#elif __has_builtin(__builtin_amdgcn_mfma_f32_16x16x16bf16_1k)
  #define MFMA_PV16(a,b,c) __builtin_amdgcn_mfma_f32_16x16x16bf16_1k(a,b,c,0,0,0)
  #define HAVE_PV16 1
#else
  #define HAVE_PV16 0
#endif

#if __has_builtin(__builtin_amdgcn_global_load_lds)
  #define HAVE_GLL 1
#else
  #define HAVE_GLL 0
#endif

__device__ inline float bf2f(unsigned short u) {
    union { unsigned int i; float f; } v; v.i = ((unsigned int)u) << 16; return v.f;
}
__device__ inline unsigned short f2bfbits(float f) {
    bf16 h = __float2bfloat16(f);
    return __builtin_bit_cast(unsigned short, h);
}

// --------------------------------------------------------------------------
#define N_X    (MTOT*DD)
#define N_COND (MTOT*CC)
#define N_WQW  (DD*DD)
#define N_WQB  (DD)
#define N_WVW  (DD*DD)
#define N_WVB  (DD)
#define N_WKW  (CC*DD*DD)
#define N_WKB  (CC*DD)
#define N_WOW  (DD*DD)
#define N_WOB  (DD)
#define P0 0
#define P1 (P0+N_X)
#define P2 (P1+N_COND)
#define P3 (P2+N_WQW)
#define P4 (P3+N_WQB)
#define P5 (P4+N_WVW)
#define P6 (P5+N_WVB)
#define P7 (P6+N_WKW)
#define P8 (P7+N_WKB)
#define P9 (P8+N_WOW)
#define PTOT (P9+N_WOB)

// --------------------------------------------------------------------------
// Fused dtype-detect + conversion. Each block self-detects from 256 sampled
// words of x (fp32 N(0,1): ~all in [1e-4,1e4]; bf16-pair-garbage: ~none).
// Block 0 publishes the flag for the final GEMM's epilogue.
// --------------------------------------------------------------------------
__global__ void convert_all(const void* s0, const void* s1, const void* s2,
                            const void* s3, const void* s4, const void* s5,
                            const void* s6, const void* s7, const void* s8,
                            const void* s9, bf16* dst, int* flagw)
{
    __shared__ int cnts[4];
    {
        const float* xf = (const float*)s0;
        float v = fabsf(xf[threadIdx.x]);
        bool ok = (v == v) && v > 1e-4f && v < 1e4f;
        unsigned long long m = __ballot(ok);
        if ((threadIdx.x & 63) == 0) cnts[threadIdx.x >> 6] = __popcll(m);
    }
    __syncthreads();
    const bool f32 = (cnts[0] + cnts[1] + cnts[2] + cnts[3]) > 128;
    if (blockIdx.x == 0 && threadIdx.x == 0) *flagw = f32 ? 1 : 0;

    size_t i = ((size_t)blockIdx.x * 256 + threadIdx.x) * 8;
    const size_t stride = (size_t)gridDim.x * 256 * 8;
    for (; i < (size_t)PTOT; i += stride) {
        const void* src; size_t off;
        if      (i < P1) { src = s0; off = i - P0; }
        else if (i < P2) { src = s1; off = i - P1; }
        else if (i < P3) { src = s2; off = i - P2; }
        else if (i < P4) { src = s3; off = i - P3; }
        else if (i < P5) { src = s4; off = i - P4; }
        else if (i < P6) { src = s5; off = i - P5; }
        else if (i < P7) { src = s6; off = i - P6; }
        else if (i < P8) { src = s7; off = i - P7; }
        else if (i < P9) { src = s8; off = i - P8; }
        else             { src = s9; off = i - P9; }
        if (f32) {
            const float* s = (const float*)src + off;
            float4 a = *(const float4*)(s);
            float4 b = *(const float4*)(s + 4);
            __align__(16) unsigned short t[8];
            t[0] = f2bfbits(a.x); t[1] = f2bfbits(a.y);
            t[2] = f2bfbits(a.z); t[3] = f2bfbits(a.w);
            t[4] = f2bfbits(b.x); t[5] = f2bfbits(b.y);
            t[6] = f2bfbits(b.z); t[7] = f2bfbits(b.w);
            *(uint4*)(dst + i) = *(const uint4*)t;
        } else {
            *(uint4*)(dst + i) = *(const uint4*)((const unsigned short*)src + off);
        }
    }
}

// ---------------------------------------------------------------------------
// GEMM body (R3-validated): Y[m,n] = sum_k X[m,k]*W[n,k] + bias[n].
// ---------------------------------------------------------------------------
__device__ __forceinline__ void gemm_body(const bf16* __restrict__ X, const bf16* __restrict__ W,
                                          const bf16* __restrict__ bias, void* __restrict__ Yv,
                                          const int* __restrict__ flagp, int flex_out, int vt_out,
                                          unsigned short* smem, int m0, int n0)
{
    const int LDT = 264;
    unsigned short* xs = smem;
    unsigned short* ws = smem + 64 * 264;
    const int t = threadIdx.x;

    for (int i = 0; i < 8; ++i) {
        int c = t + i * 256;
        int row = c >> 5, col = (c & 31) * 8;
        *(uint4*)&xs[row * LDT + col] = *(const uint4*)(X + (size_t)(m0 + row) * DD + col);
        *(uint4*)&ws[row * LDT + col] = *(const uint4*)(W + (size_t)(n0 + row) * DD + col);
    }
    __syncthreads();

    const int w = t >> 6, lane = t & 63;
    const int lrow = lane & 15, lk = (lane >> 4) * 8, rgrp = (lane >> 4) * 4;
    floatx4 acc[4] = {};
    const unsigned short* ax = &xs[(w * 16 + lrow) * LDT + lk];
    for (int kt = 0; kt < 8; ++kt) {
        short8 a = *(const short8*)(ax + kt * 32);
        #pragma unroll
        for (int j = 0; j < 4; ++j) {
            short8 b = *(const short8*)&ws[(j * 16 + lrow) * LDT + kt * 32 + lk];
            acc[j] = __builtin_amdgcn_mfma_f32_16x16x32_bf16(a, b, acc[j], 0, 0, 0);
        }
    }

    if (vt_out) {
        __syncthreads();
        unsigned short* ts = xs;
        #pragma unroll
        for (int j = 0; j < 4; ++j) {
            float bv = __bfloat162float(bias[n0 + j * 16 + lrow]);
            #pragma unroll
            for (int r = 0; r < 4; ++r)
                ts[(j * 16 + lrow) * 72 + w * 16 + rgrp + r] = f2bfbits(acc[j][r] + bv);
        }
        __syncthreads();
        const int bq = m0 >> 11, s0v = m0 & 2047, h = n0 >> 6;
        bf16* dstb = (bf16*)Yv + ((size_t)(bq * HH + h) * HD) * SS + s0v;
        for (int i = 0; i < 2; ++i) {
            int idx = t + i * 256, row = idx >> 3, ch = (idx & 7) * 8;
            *(uint4*)(dstb + (size_t)row * SS + ch) = *(const uint4*)&ts[row * 72 + ch];
        }
        return;
    }

    const bool f32o = flex_out && (*flagp != 0);
    #pragma unroll
    for (int j = 0; j < 4; ++j) {
        int col = n0 + j * 16 + lrow;
        float bv = __bfloat162float(bias[col]);
        #pragma unroll
        for (int r = 0; r < 4; ++r) {
            int row = m0 + w * 16 + rgrp + r;
            float val = acc[j][r] + bv;
            if (f32o) ((float*)Yv)[(size_t)row * DD + col] = val;
            else      ((bf16*)Yv)[(size_t)row * DD + col] = __float2bfloat16(val);
        }
    }
}

// Merged Q-proj + V-proj: homogeneous blocks (same LDS/VGPR class), one launch.
__launch_bounds__(256, 2)
__global__ void gemm_qv(const bf16* __restrict__ X,
                        const bf16* __restrict__ Wqw, const bf16* __restrict__ Wqb, bf16* __restrict__ Qout,
                        const bf16* __restrict__ Wvw, const bf16* __restrict__ Wvb, bf16* __restrict__ Vout,
                        const int* __restrict__ flagp)
{
    __shared__ __align__(16) unsigned short smem[2 * 64 * 264];
    int gi = blockIdx.x;
    if (gi < 1024) {
        int n0 = (gi & 3) * 64, m0 = (gi >> 2) * 64;
        gemm_body(X, Wqw, Wqb, (void*)Qout, flagp, 0, 0, smem, m0, n0);
    } else {
        gi -= 1024;
        int n0 = (gi & 3) * 64, m0 = (gi >> 2) * 64;
        gemm_body(X, Wvw, Wvb, (void*)Vout, flagp, 0, 1, smem, m0, n0);
    }
}

// standalone gemm for the output projection
__launch_bounds__(256, 2)
__global__ void gemm_bias(const bf16* __restrict__ X, const bf16* __restrict__ W,
                          const bf16* __restrict__ bias, void* __restrict__ Yv,
                          const int* __restrict__ flagp, int flex_out, int vt_out)
{
    __shared__ __align__(16) unsigned short smem[2 * 64 * 264];
    gemm_body(X, W, bias, Yv, flagp, flex_out, vt_out, smem, blockIdx.y * 64, blockIdx.x * 64);
}

// ---------------------------------------------------------------------------
// Class-dependent key — R6-exact (validated 78 us): 256 thr / 4 waves,
// 128 rows x 64 cols, 2 m-tiles per wave, X in registers, Wk ping-pong via
// global_load_lds + XOR chunk swizzle.
// ---------------------------------------------------------------------------
__device__ __forceinline__ void stage_ws4(const bf16* __restrict__ Wc,
                                          unsigned short* wsbuf, int w, int lane)
{
    #pragma unroll
    for (int i = 0; i < 8; ++i) {
        int rr = w * 16 + i * 2 + (lane >> 5);
        int cs = (lane & 31) ^ (rr & 7);
        const bf16* src = Wc + (size_t)rr * DD + cs * 8;
        unsigned short* dst = wsbuf + (size_t)(w * 16 + i * 2) * DD;
#if HAVE_GLL
        __builtin_amdgcn_global_load_lds(
            (const __attribute__((address_space(1))) void*)src,
            (__attribute__((address_space(3))) void*)dst, 16, 0, 0);
#else
        uint4 v = *(const uint4*)src;
        *(uint4*)(dst + (size_t)lane * 8) = v;
#endif
    }
}

__launch_bounds__(256, 2)
__global__ void classkey(const bf16* __restrict__ X, const bf16* __restrict__ Cond,
                         const bf16* __restrict__ Wk, const bf16* __restrict__ Wkb,
                         bf16* __restrict__ Kout)
{
    __shared__ __align__(16) unsigned short ws[2][64 * 256];
    __shared__ __align__(16) unsigned short conds[128 * 32];
    __shared__ __align__(16) unsigned short kbs[32 * 64];
    const int t    = threadIdx.x;
    const int w    = t >> 6;
    const int lane = t & 63;
    const int r16  = lane & 15;
    const int quad = lane >> 4;
    const int m0   = blockIdx.y * 128;
    const int n0   = blockIdx.x * 64;

    #pragma unroll
    for (int i = 0; i < 2; ++i) {
        int chunk = t + i * 256;
        int row = chunk >> 2, c8 = (chunk & 3) * 8;
        *(uint4*)&conds[row * 32 + c8] = *(const uint4*)(Cond + (size_t)(m0 + row) * CC + c8);
    }
    {
        int row = t >> 3, c8 = (t & 7) * 8;
        *(uint4*)&kbs[row * 64 + c8] = *(const uint4*)(Wkb + (size_t)row * DD + n0 + c8);
    }

    short8 xa[2][8];
    #pragma unroll
    for (int mt = 0; mt < 2; ++mt) {
        const bf16* xrow = X + (size_t)(m0 + w * 32 + mt * 16 + r16) * DD + quad * 8;
        #pragma unroll
        for (int kt = 0; kt < 8; ++kt)
            xa[mt][kt] = *(const short8*)(xrow + kt * 32);
    }

    stage_ws4(Wk + (size_t)n0 * DD, &ws[0][0], w, lane);

    floatx4 acck[2][4] = {};
    for (int c = 0; c < CC; ++c) {
        __syncthreads();
        if (c + 1 < CC)
            stage_ws4(Wk + (size_t)(c + 1) * DD * DD + (size_t)n0 * DD,
                      &ws[(c + 1) & 1][0], w, lane);

        const unsigned short* wb = &ws[c & 1][0];
        floatx4 p[2][4] = {};
        #pragma unroll
        for (int kt = 0; kt < 8; ++kt) {
            short8 bj[4];
            #pragma unroll
            for (int j = 0; j < 4; ++j)
                bj[j] = *(const short8*)&wb[(j * 16 + r16) * DD +
                                            (((kt * 4 + quad) ^ (r16 & 7)) << 3)];
            #pragma unroll
            for (int mt = 0; mt < 2; ++mt)
                #pragma unroll
                for (int j = 0; j < 4; ++j)
                    p[mt][j] = __builtin_amdgcn_mfma_f32_16x16x32_bf16(xa[mt][kt], bj[j], p[mt][j], 0, 0, 0);
        }
        #pragma unroll
        for (int mt = 0; mt < 2; ++mt)
            #pragma unroll
            for (int r = 0; r < 4; ++r) {
                float cv = bf2f(conds[(w * 32 + mt * 16 + quad * 4 + r) * 32 + c]);
                #pragma unroll
                for (int j = 0; j < 4; ++j) acck[mt][j][r] += cv * p[mt][j][r];
            }
    }

    float kbv[2][4][4] = {};
    for (int c = 0; c < CC; ++c) {
        #pragma unroll
        for (int mt = 0; mt < 2; ++mt)
            #pragma unroll
            for (int r = 0; r < 4; ++r) {
                float cf = bf2f(conds[(w * 32 + mt * 16 + quad * 4 + r) * 32 + c]);
                #pragma unroll
                for (int j = 0; j < 4; ++j)
                    kbv[mt][j][r] += cf * bf2f(kbs[c * 64 + j * 16 + r16]);
            }
    }
    #pragma unroll
    for (int mt = 0; mt < 2; ++mt)
        #pragma unroll
        for (int j = 0; j < 4; ++j) {
            int col = n0 + j * 16 + r16;
            #pragma unroll
            for (int r = 0; r < 4; ++r) {
                int row = m0 + w * 32 + mt * 16 + quad * 4 + r;
                Kout[(size_t)row * DD + col] = __float2bfloat16(acck[mt][j][r] + kbv[mt][j][r]);
            }
        }
}

// ---------------------------------------------------------------------------
// Flash attention v2 (unchanged from R5 — validated).
// ---------------------------------------------------------------------------
__device__ inline void stage_kv(const bf16* __restrict__ kRow,
                                const bf16* __restrict__ vRow,
                                unsigned short* kbuf, unsigned short* vbuf,
                                int w, int lane)
{
    int r  = w * 8 + (lane >> 3);
    int cs = (lane & 7) ^ (r & 7);
#if HAVE_GLL
    __builtin_amdgcn_global_load_lds(
        (const __attribute__((address_space(1))) void*)(kRow + (size_t)r * DD + cs * 8),
        (__attribute__((address_space(3))) void*)(kbuf + w * 512), 16, 0, 0);
    __builtin_amdgcn_global_load_lds(
        (const __attribute__((address_space(1))) void*)(vRow + (size_t)r * SS + cs * 8),
        (__attribute__((address_space(3))) void*)(vbuf + w * 512), 16, 0, 0);
#else
    *(uint4*)(kbuf + w * 512 + (size_t)lane * 8) = *(const uint4*)(kRow + (size_t)r * DD + cs * 8);
    *(uint4*)(vbuf + w * 512 + (size_t)lane * 8) = *(const uint4*)(vRow + (size_t)r * SS + cs * 8);
#endif
}

__launch_bounds__(512, 4)
__global__ void attn(const bf16* __restrict__ Q, const bf16* __restrict__ Kb,
                     const bf16* __restrict__ VT, bf16* __restrict__ O)
{
    __shared__ __align__(16) unsigned short ks[2][64 * 64];
    __shared__ __align__(16) unsigned short vt[2][64 * 64];
#if !HAVE_PV16
    __shared__ __align__(16) unsigned short ps[128 * 72];
#endif
    const int t    = threadIdx.x;
    const int w    = t >> 6;
    const int lane = t & 63;
    const int r16  = lane & 15;
    const int quad = lane >> 4;
    const int bh   = blockIdx.y;
    const int b    = bh >> 2, h = bh & 3;
    const int q0   = blockIdx.x * 128;
    const size_t base  = ((size_t)b * SS) * DD + h * HD;
    const size_t vbase = (size_t)bh * HD * SS;

    short8 qa[2];
    {
        const bf16* qrow = Q + base + (size_t)(q0 + w * 16 + r16) * DD + quad * 8;
        #pragma unroll
        for (int k2 = 0; k2 < 2; ++k2) {
            short8 raw = *(const short8*)(qrow + k2 * 32);
            short8 sc;
            #pragma unroll
            for (int e = 0; e < 8; ++e)
                sc[e] = (short)f2bfbits(bf2f((unsigned short)raw[e]) * 0.125f);
            qa[k2] = sc;
        }
    }

    stage_kv(Kb + base, VT + vbase, &ks[0][0], &vt[0][0], w, lane);

    floatx4 acco[4] = {};
    float mrun = -1e30f, lrun = 0.f;

    for (int kt = 0; kt < SS / 64; ++kt) {
        __syncthreads();
        if (kt + 1 < SS / 64)
            stage_kv(Kb + base + (size_t)(kt + 1) * 64 * DD,
                     VT + vbase + (size_t)(kt + 1) * 64,
                     &ks[(kt + 1) & 1][0], &vt[(kt + 1) & 1][0], w, lane);

        const unsigned short* kbuf = &ks[kt & 1][0];
        const unsigned short* vbuf = &vt[kt & 1][0];

        floatx4 s[4] = {};
        #pragma unroll
        for (int k2 = 0; k2 < 2; ++k2) {
            short8 bq = qa[k2];
            #pragma unroll
            for (int j = 0; j < 4; ++j) {
                short8 ak = *(const short8*)&kbuf[(j * 16 + r16) * 64 +
                                                  (((k2 * 4 + quad) ^ (r16 & 7)) << 3)];
                s[j] = __builtin_amdgcn_mfma_f32_16x16x32_bf16(ak, bq, s[j], 0, 0, 0);
            }
        }

        float mx = -1e30f;
        #pragma unroll
        for (int j = 0; j < 4; ++j)
            #pragma unroll
            for (int r = 0; r < 4; ++r) mx = fmaxf(mx, s[j][r]);
        mx = fmaxf(mx, __shfl_xor(mx, 16, 64));
        mx = fmaxf(mx, __shfl_xor(mx, 32, 64));
        float mnew  = fmaxf(mrun, mx);
        float alpha = __expf(mrun - mnew);
        float sum = 0.f;
        #pragma unroll
        for (int j = 0; j < 4; ++j)
            #pragma unroll
            for (int r = 0; r < 4; ++r) {
                float e = __expf(s[j][r] - mnew);
                s[j][r] = e; sum += e;
            }
        sum += __shfl_xor(sum, 16, 64);
        sum += __shfl_xor(sum, 32, 64);
        lrun = lrun * alpha + sum;
        mrun = mnew;

        #pragma unroll
        for (int r = 0; r < 4; ++r) {
            float ar = __shfl(alpha, (quad << 4) + quad * 4 + r, 64);
            #pragma unroll
            for (int jn = 0; jn < 4; ++jn) acco[jn][r] *= ar;
        }

#if HAVE_PV16
        #pragma unroll
        for (int j = 0; j < 4; ++j) {
            short4v p;
            p[0] = (short)f2bfbits(s[j][0]); p[1] = (short)f2bfbits(s[j][1]);
            p[2] = (short)f2bfbits(s[j][2]); p[3] = (short)f2bfbits(s[j][3]);
            #pragma unroll
            for (int jn = 0; jn < 4; ++jn) {
                short4v vv = *(const short4v*)&vbuf[(jn * 16 + r16) * 64 +
                                                    ((((j * 2) + (quad >> 1)) ^ (r16 & 7)) << 3) +
                                                    (quad & 1) * 4];
                acco[jn] = MFMA_PV16(p, vv, acco[jn]);
            }
        }
#else
        #pragma unroll
        for (int j = 0; j < 4; ++j)
            #pragma unroll
            for (int r = 0; r < 4; ++r)
                ps[(w * 16 + r16) * 72 + j * 16 + quad * 4 + r] = f2bfbits(s[j][r]);
        #pragma unroll
        for (int k2 = 0; k2 < 2; ++k2) {
            short8 a = *(const short8*)&ps[(w * 16 + r16) * 72 + k2 * 32 + quad * 8];
            #pragma unroll
            for (int jn = 0; jn < 4; ++jn) {
                short8 bb = *(const short8*)&vbuf[(jn * 16 + r16) * 64 +
                                                  (((k2 * 4 + quad) ^ (r16 & 7)) << 3)];
                acco[jn] = __builtin_amdgcn_mfma_f32_16x16x32_bf16(a, bb, acco[jn], 0, 0, 0);
            }
        }
#endif
    }

    #pragma unroll
    for (int r = 0; r < 4; ++r) {
        float lr = __shfl(lrun, (quad << 4) + quad * 4 + r, 64);
        float inv = 1.0f / lr;
        int row = q0 + w * 16 + quad * 4 + r;
        #pragma unroll
        for (int jn = 0; jn < 4; ++jn)
            O[base + (size_t)row * DD + jn * 16 + r16] = __float2bfloat16(acco[jn][r] * inv);
    }
}

// ---------------------------------------------------------------------------
extern "C" void kernel_launch(void* const* d_in, const int* in_sizes, int n_in,
                              void* d_out, int out_size, void* d_ws, size_t ws_size,
                              hipStream_t stream)
{
    int*  flag = (int*)d_ws;
    bf16* conv = (bf16*)((char*)d_ws + 256);

    const bf16* xb    = conv + P0;
    const bf16* condb = conv + P1;
    const bf16* wqw   = conv + P2;
    const bf16* wqb   = conv + P3;
    const bf16* wvw   = conv + P4;
    const bf16* wvb   = conv + P5;
    const bf16* wkw   = conv + P6;
    const bf16* wkb   = conv + P7;
    const bf16* wow   = conv + P8;
    const bf16* wob   = conv + P9;

    bf16* qb = conv + PTOT;
    bf16* kb = qb + (size_t)MTOT * DD;
    bf16* vb = kb + (size_t)MTOT * DD;   // V^T layout [b*H+h][hd][S]
    bf16* ob = vb + (size_t)MTOT * DD;

    dim3 blk(256);
    hipLaunchKernelGGL(convert_all, dim3((PTOT / 8 + 255) / 256), blk, 0, stream,
                       d_in[0], d_in[1], d_in[2], d_in[3], d_in[4],
                       d_in[5], d_in[6], d_in[7], d_in[8], d_in[9],
                       conv, flag);

    dim3 gck(DD / 64, MTOT / 128);       // (4, 128), 256-thread blocks
    hipLaunchKernelGGL(classkey, gck, blk, 0, stream, xb, condb, wkw, wkb, kb);

    hipLaunchKernelGGL(gemm_qv, dim3(2048), blk, 0, stream,
                       xb, wqw, wqb, qb, wvw, wvb, vb, flag);

    dim3 ga(SS / 128, BB * HH);          // (16, 32), 512-thread blocks
    hipLaunchKernelGGL(attn, ga, dim3(512), 0, stream, qb, kb, vb, ob);

    dim3 gg(DD / 64, MTOT / 64);
    hipLaunchKernelGGL(gemm_bias, gg, blk, 0, stream, ob, wow, wob, d_out, flag, 1, 0);
}